// Round 3
// baseline (213.189 us; speedup 1.0000x reference)
//
#include <hip/hip_runtime.h>
#include <math.h>

#define NB 16
#define NC 512
#define NK 128
#define SP 4096   // 64*64 spatial positions

typedef __attribute__((ext_vector_type(8))) short short8;
typedef __attribute__((ext_vector_type(4))) float f32x4;

__device__ inline unsigned short f2bf(float f) {
    unsigned int u = __builtin_bit_cast(unsigned int, f);
    u += 0x7fffu + ((u >> 16) & 1u);   // RNE
    return (unsigned short)(u >> 16);
}

// ---------------------------------------------------------------------------
// ws layout (float offsets):
//   [0    .. 2047 ]  SY    : sum over pos of relu(wb*x+bb), per (b,k)
//   [2048 .. 4095 ]  SX1
//   [4096 .. 6143 ]  SX2
//   [6144 .. 22527]  sbr   : sigmoid outputs, 2 br * 16 b * 512 c
//   [22528.. 55295]  w0bf  : bf16 wb[k][c]                    (65536 ushort)
//   [55296.. 88063]  w1bf  : bf16 wa[k][64a+b]=wa[k][8b+a]    (65536 ushort)
// ---------------------------------------------------------------------------

__global__ __launch_bounds__(256) void prep_weights(
    const float* __restrict__ wa, const float* __restrict__ wb,
    unsigned short* __restrict__ w0, unsigned short* __restrict__ w1) {
    int e = blockIdx.x * 256 + threadIdx.x;   // 0..65535
    w0[e] = f2bf(wb[e]);                      // same [k][c] layout
    int k = e >> 9, rem = e & 511, q = rem >> 6, t = rem & 63;
    w1[e] = f2bf(wa[k * 512 + 8 * t + q]);
}

// ---------------------------------------------------------------------------
// Fused view1 + view2 conv+mean kernel.
// Block (j, b), 512 threads (8 waves). Owns planes P[q] = x[b, 64q + j, :, :].
//   view1: fX1[p=j, h] = relu(sum_{i1} w1[k,i1] * P[i1>>6][i1&63][h] + ba[k])
//   view2: fX2[w2, h2=j] = relu(sum_{i2} w1[k,i2] * P[w2&7][8*(i2>>6)+(w2>>3)][i2&63] + ba)
// Both share the same bf16 weight tile per K-chunk.
// act LDS: plane stride 4368 elems, row stride 68 elems (bank spreading).
// ---------------------------------------------------------------------------
#define PLS 4368   // plane stride (elems) = 64*68 + 16
#define RWS 68     // row stride (elems)

__global__ __launch_bounds__(512, 1) void conv_fused12(
    const float* __restrict__ x, const unsigned short* __restrict__ w1bf,
    const float* __restrict__ ba, float* __restrict__ SX1, float* __restrict__ SX2) {
    __shared__ __align__(16) unsigned short actS[8 * PLS];   // 69888 B
    __shared__ __align__(16) unsigned short wS[128 * 128];   // 32768 B, XOR-swizzled granules
    __shared__ float red1[NK];
    __shared__ float red2[NK];

    const int b = blockIdx.y;
    const int j = blockIdx.x;
    const int t = threadIdx.x;
    const int lane = t & 63;
    const int wv = t >> 6;          // 0..7
    const int ph = wv >> 2;         // pos half (32 rows)
    const int kq = wv & 3;          // k-out quarter (32 cols = 2 n-tiles)
    const int lr = lane & 15;
    const int lg = lane >> 4;       // 0..3

    if (t < NK) { red1[t] = 0.f; red2[t] = 0.f; }

    // ---- stage all 8 planes as bf16, natural layout, padded ----
#pragma unroll
    for (int it = 0; it < 16; ++it) {
        int idx = it * 512 + t;            // 8192 float4 chunks
        int row = idx >> 4;                // 0..511 = 64q + wloc
        int h4 = idx & 15;
        int q = row >> 6, wloc = row & 63;
        float4 v = *(const float4*)(x + (size_t)(b * NC + 64 * q + j) * SP + wloc * 64 + h4 * 4);
        ushort4 u;
        u.x = f2bf(v.x); u.y = f2bf(v.y); u.z = f2bf(v.z); u.w = f2bf(v.w);
        *(ushort4*)(&actS[q * PLS + wloc * RWS + h4 * 4]) = u;
    }

    f32x4 acc1[2][2], acc2[2][2];
#pragma unroll
    for (int pt = 0; pt < 2; ++pt)
#pragma unroll
        for (int nt = 0; nt < 2; ++nt) { acc1[pt][nt] = (f32x4)(0.f); acc2[pt][nt] = (f32x4)(0.f); }

    for (int wc = 0; wc < 4; ++wc) {
        // ---- stage weight chunk [128 kout][128 i], granule-swizzled ----
#pragma unroll
        for (int it = 0; it < 4; ++it) {
            int gi = it * 512 + t;          // 2048 granules of 16 B
            int k = gi >> 4, g = gi & 15;
            uint4 v = *(const uint4*)(w1bf + (size_t)k * 512 + wc * 128 + g * 8);
            *(uint4*)((char*)wS + k * 256 + (((g ^ (k & 7))) << 4)) = v;
        }
        __syncthreads();

#pragma unroll
        for (int kk = 0; kk < 4; ++kk) {
            // shared B-frags for this K-32 step (2 n-tiles)
            short8 bf[2];
#pragma unroll
            for (int nt = 0; nt < 2; ++nt) {
                int krow = kq * 32 + nt * 16 + lr;
                int g = kk * 4 + lg;
                bf[nt] = *(const short8*)((char*)wS + krow * 256 + ((g ^ (krow & 7)) << 4));
            }
            const int qoff = (kk >= 2) ? 1 : 0;        // (kk*32+lg*8)>>6
            const int off63 = (kk & 1) * 32 + lg * 8;  // (kk*32+lg*8)&63

#pragma unroll
            for (int pt = 0; pt < 2; ++pt) {
                const int pos = ph * 32 + pt * 16 + lr;
                // ---- view1 A-frag: 8 strided u16 (rows i1, fixed h=pos) ----
                int base1 = (2 * wc + qoff) * PLS + off63 * RWS + pos;
                short8 a1;
#pragma unroll
                for (int e = 0; e < 8; ++e) a1[e] = (short)actS[base1 + RWS * e];
                // ---- view2 A-frag: contiguous 8 (fixed row, h=ihi) ----
                int q2 = pos & 7, w2hi = pos >> 3;
                int ilo = 2 * wc + qoff;
                int e2 = q2 * PLS + (8 * ilo + w2hi) * RWS + off63;
                ushort4 lo = *(const ushort4*)(&actS[e2]);
                ushort4 hi = *(const ushort4*)(&actS[e2 + 4]);
                short8 a2;
                a2[0] = (short)lo.x; a2[1] = (short)lo.y; a2[2] = (short)lo.z; a2[3] = (short)lo.w;
                a2[4] = (short)hi.x; a2[5] = (short)hi.y; a2[6] = (short)hi.z; a2[7] = (short)hi.w;
#pragma unroll
                for (int nt = 0; nt < 2; ++nt) {
                    acc1[pt][nt] = __builtin_amdgcn_mfma_f32_16x16x32_bf16(a1, bf[nt], acc1[pt][nt], 0, 0, 0);
                    acc2[pt][nt] = __builtin_amdgcn_mfma_f32_16x16x32_bf16(a2, bf[nt], acc2[pt][nt], 0, 0, 0);
                }
            }
        }
        __syncthreads();
    }

    // ---- epilogue: relu(acc+bias), sum positions, accumulate ----
#pragma unroll
    for (int pt = 0; pt < 2; ++pt)
#pragma unroll
        for (int nt = 0; nt < 2; ++nt) {
            int k = kq * 32 + nt * 16 + lr;
            float bv = ba[k];
            float s1 = 0.f, s2 = 0.f;
#pragma unroll
            for (int rr = 0; rr < 4; ++rr) {
                s1 += fmaxf(acc1[pt][nt][rr] + bv, 0.f);
                s2 += fmaxf(acc2[pt][nt][rr] + bv, 0.f);
            }
            atomicAdd(&red1[k], s1);
            atomicAdd(&red2[k], s2);
        }
    __syncthreads();
    if (t < NK) {
        atomicAdd(&SX1[b * NK + t], red1[t]);
        atomicAdd(&SX2[b * NK + t], red2[t]);
    }
}

// ---------------------------------------------------------------------------
// view0 conv (round-2 verified structure, float4-vectorized staging loads)
// ---------------------------------------------------------------------------
__global__ __launch_bounds__(256) void conv_mfma0(
    const float* __restrict__ x, const unsigned short* __restrict__ wbf,
    const float* __restrict__ bias, float* __restrict__ Ssum) {
    __shared__ __align__(16) unsigned short actS[64 * 128];   // 16 KB swizzled
    __shared__ __align__(16) unsigned short wS[128 * 128];    // 32 KB swizzled
    __shared__ float red[NK];

    const int b = blockIdx.y;
    const int g = blockIdx.x;
    const int t = threadIdx.x;
    const int wv = t >> 6;
    const int lane = t & 63;
    const int lr = lane & 15, lg = lane >> 4;

    if (t < NK) red[t] = 0.f;

    f32x4 acc[8];
#pragma unroll
    for (int n = 0; n < 8; ++n) acc[n] = (f32x4)(0.f);

    for (int ch = 0; ch < 4; ++ch) {
        // stage weight chunk [128 k][128 i]
#pragma unroll
        for (int it = 0; it < 8; ++it) {
            int gi = it * 256 + t;
            int k = gi >> 4, gg = gi & 15;
            uint4 v = *(const uint4*)(wbf + (size_t)k * 512 + ch * 128 + gg * 8);
            *(uint4*)((char*)wS + k * 256 + ((gg ^ (k & 7)) << 4)) = v;
        }
        // stage act chunk: 128 c-rows x 64 pos, float4 loads + transposed b16 writes
#pragma unroll
        for (int it = 0; it < 8; ++it) {
            int idx = it * 256 + t;         // 2048 float4
            int row = idx >> 4;             // c-local 0..127
            int p4 = idx & 15;
            float4 v = *(const float4*)(x + (size_t)(b * NC + ch * 128 + row) * SP + g * 64 + p4 * 4);
            float vv[4] = {v.x, v.y, v.z, v.w};
#pragma unroll
            for (int m = 0; m < 4; ++m) {
                int pos = p4 * 4 + m;
                int byte = pos * 256 + ((((row >> 3) ^ (pos & 7))) << 4) + (row & 7) * 2;
                *(unsigned short*)((char*)actS + byte) = f2bf(vv[m]);
            }
        }
        __syncthreads();
#pragma unroll
        for (int kk = 0; kk < 4; ++kk) {
            int prow = wv * 16 + lr;
            int ig = 4 * kk + lg;
            short8 a = *(const short8*)((const char*)actS + prow * 256 +
                                        ((ig ^ (prow & 7)) << 4));
#pragma unroll
            for (int n = 0; n < 8; ++n) {
                int krow = n * 16 + lr;
                short8 bfr = *(const short8*)((const char*)wS + krow * 256 +
                                              ((ig ^ (krow & 7)) << 4));
                acc[n] = __builtin_amdgcn_mfma_f32_16x16x32_bf16(a, bfr, acc[n], 0, 0, 0);
            }
        }
        __syncthreads();
    }

#pragma unroll
    for (int n = 0; n < 8; ++n) {
        int k = n * 16 + lr;
        float bv = bias[k];
        float s = 0.f;
#pragma unroll
        for (int rr = 0; rr < 4; ++rr) s += fmaxf(acc[n][rr] + bv, 0.f);
        atomicAdd(&red[k], s);
    }
    __syncthreads();
    if (t < NK) atomicAdd(&Ssum[b * NK + t], red[t]);
}

// Per-(b,branch) MLP chain
__global__ __launch_bounds__(256) void chain_kernel(
    const float* __restrict__ Sy, const float* __restrict__ Sx1,
    const float* __restrict__ Sx2, const float* __restrict__ wd,
    const float* __restrict__ wc1, const float* __restrict__ bc1,
    const float* __restrict__ wc2, const float* __restrict__ bc2,
    float* __restrict__ sbr) {
    __shared__ float m[128];
    __shared__ float ap[512];
    __shared__ float z[128];
    const int b = blockIdx.x, br = blockIdx.y, t = threadIdx.x;
    const float* Sx = (br == 0) ? Sx1 : Sx2;
    const float inv = 1.0f / 4096.0f;

    if (t < 128) m[t] = (Sy[b * NK + t] + Sx[b * NK + t]) * inv;
    __syncthreads();
    for (int c = t; c < NC; c += 256) {
        float v = 0.f;
        for (int k = 0; k < NK; ++k) v += wd[c * NK + k] * m[k];
        ap[c] = v;
    }
    __syncthreads();
    if (t < 128) {
        float v = bc1[t];
        for (int c = 0; c < NC; ++c) v += wc1[t * NC + c] * ap[c];
        z[t] = fmaxf(v, 0.f);
    }
    __syncthreads();
    for (int c = t; c < NC; c += 256) {
        float v = bc2[c];
        for (int k = 0; k < NK; ++k) v += wc2[c * NK + k] * z[k];
        sbr[(br * NB + b) * NC + c] = 1.f / (1.f + expf(-v));
    }
}

// out[b,c,s] = x[b,c,s] + s1[b,c] + s2[b,c]
__global__ __launch_bounds__(256) void final_add(
    const float* __restrict__ x, const float* __restrict__ sbr,
    float* __restrict__ out) {
    const int total4 = NB * NC * SP / 4;   // 8388608
    for (int i = blockIdx.x * 256 + threadIdx.x; i < total4; i += gridDim.x * 256) {
        int flat = i * 4;
        int bc = flat >> 12;
        int b = bc >> 9, c = bc & 511;
        float s = sbr[b * NC + c] + sbr[NB * NC + b * NC + c];
        float4 xv = ((const float4*)x)[i];
        float4 o = {xv.x + s, xv.y + s, xv.z + s, xv.w + s};
        ((float4*)out)[i] = o;
    }
}

extern "C" void kernel_launch(void* const* d_in, const int* in_sizes, int n_in,
                              void* d_out, int out_size, void* d_ws, size_t ws_size,
                              hipStream_t stream) {
    const float* x   = (const float*)d_in[0];
    const float* wa  = (const float*)d_in[1];
    const float* ba  = (const float*)d_in[2];
    const float* wb  = (const float*)d_in[3];
    const float* bb  = (const float*)d_in[4];
    const float* wd  = (const float*)d_in[5];
    const float* wc1 = (const float*)d_in[6];
    const float* bc1 = (const float*)d_in[7];
    const float* wc2 = (const float*)d_in[8];
    const float* bc2 = (const float*)d_in[9];
    float* out = (float*)d_out;

    float* ws  = (float*)d_ws;
    float* SY  = ws;
    float* SX1 = ws + 2048;
    float* SX2 = ws + 4096;
    float* sbr = ws + 6144;
    unsigned short* w0bf = (unsigned short*)(ws + 22528);
    unsigned short* w1bf = (unsigned short*)(ws + 55296);

    hipMemsetAsync(ws, 0, 6144 * sizeof(float), stream);
    prep_weights<<<256, 256, 0, stream>>>(wa, wb, w0bf, w1bf);
    conv_fused12<<<dim3(64, NB), 512, 0, stream>>>(x, w1bf, ba, SX1, SX2);
    conv_mfma0<<<dim3(64, NB), 256, 0, stream>>>(x, w0bf, bb, SY);
    chain_kernel<<<dim3(NB, 2), 256, 0, stream>>>(SY, SX1, SX2, wd, wc1, bc1, wc2, bc2, sbr);
    final_add<<<2048, 256, 0, stream>>>(x, sbr, out);
}